// Round 12
// baseline (87.446 us; speedup 1.0000x reference)
//
#include <hip/hip_runtime.h>

// out[b,po] = sum_k W[po,k]*x[b,k] + bias[po];  B=32, NPO=4096, K=16384.
// R6 structure + NONTEMPORAL W loads (single change): W is stream-once ->
// nt keeps it from evicting the XCD-shared x slice out of L2.
// (R11 fix: nontemporal builtin needs clang ext-vector type, not HIP float4.)
// 3 kernels: (1) precast x->bf16 (1MB in d_ws), (2) main GEMM: 256 blocks
// (128 po-groups x 2 k-halves; kh=blockIdx&1 constant per XCD -> shared
// 0.5MB-bf16 x half-slice, L2-resident), 512 thr, POT=32, 32 chunks of 256 k;
// distance-2 reg prefetch -> bf16 LDS dbuf, raw s_barrier + lgkmcnt(0) (no
// vmcnt drain); 8 waves = 2 btile x 2 potile x 2 kq, 4x mfma 16x16x32/chunk;
// fp32 partials, (3) combine adds k-halves + bias.

typedef __attribute__((ext_vector_type(8))) __bf16 bf16x8;
typedef __attribute__((ext_vector_type(4))) __bf16 bf16x4;
typedef __attribute__((ext_vector_type(4))) float f32x4;   // clang vector: ok for nontemporal

__device__ inline bf16x8 cvt8(f32x4 a, f32x4 b) {
  bf16x8 r;
  r[0] = (__bf16)a.x; r[1] = (__bf16)a.y; r[2] = (__bf16)a.z; r[3] = (__bf16)a.w;
  r[4] = (__bf16)b.x; r[5] = (__bf16)b.y; r[6] = (__bf16)b.z; r[7] = (__bf16)b.w;
  return r;
}

#define KDIM 16384
#define NPO  4096
#define POT  32
#define CHK  256
#define KH   8192
#define NCHH 32      // chunks per k-half
#define WSTR 264     // padded LDS k-stride (bf16): 528 B

__global__ __launch_bounds__(256)
void precast_x(const float* __restrict__ x, __bf16* __restrict__ xbf) {
  const int i = blockIdx.x * 256 + threadIdx.x;   // 131072 float4s
  f32x4 v = reinterpret_cast<const f32x4*>(x)[i];
  bf16x4 o;
  o[0] = (__bf16)v.x; o[1] = (__bf16)v.y; o[2] = (__bf16)v.z; o[3] = (__bf16)v.w;
  reinterpret_cast<bf16x4*>(xbf)[i] = o;
}

__global__ __launch_bounds__(512, 2)
void trace_main(const __bf16* __restrict__ xbf, const float* __restrict__ w,
                float* __restrict__ part) {
  __shared__ __bf16 wbuf[2][32 * WSTR];   // 33 KB
  __shared__ __bf16 xbuf[2][32 * WSTR];   // 33 KB
  __shared__ float  red[2048];            // 8 KB

  const int t    = threadIdx.x;
  const int lane = t & 63;
  const int wv   = t >> 6;        // 0..7
  const int btile  = wv & 1;      // 16 batches
  const int potile = (wv >> 1) & 1;
  const int kq     = wv >> 2;     // 128-k half of chunk
  const int kh    = blockIdx.x & 1;    // constant per XCD
  const int group = blockIdx.x >> 1;   // po group (32 rows)
  const int po_base = group * POT;

  // staging coords: both tiles 32 rows x 256 cols; 16 elems/thread
  const int row_s = t >> 4;
  const int col_s = (t & 15) * 16;
  const float*  wg = w   + (size_t)(po_base + row_s) * KDIM + (size_t)kh * KH + col_s;
  const __bf16* xg = xbf + (size_t)row_s * KDIM + (size_t)kh * KH + col_s;
  const int soff = row_s * WSTR + col_s;

  // fragment coords (A = x, B = w; same lane->k rule on both operands)
  const int lrow = lane & 15, lhi = lane >> 4;
  const int fk  = kq * 128 + lhi * 8;
  const int wfo = (potile * 16 + lrow) * WSTR + fk;
  const int xfo = (btile * 16 + lrow) * WSTR + fk;

  f32x4 acc = {0.f, 0.f, 0.f, 0.f};

  // W loads NONTEMPORAL (stream-once; don't evict x from L2)
#define ISSUE(W4, X2, c) do {                                            \
    const f32x4*  wp_ = (const f32x4*)(wg + (size_t)(c) * CHK);          \
    const __bf16* xp_ = xg + (size_t)(c) * CHK;                          \
    W4[0] = __builtin_nontemporal_load(wp_);                             \
    W4[1] = __builtin_nontemporal_load(wp_ + 1);                         \
    W4[2] = __builtin_nontemporal_load(wp_ + 2);                         \
    W4[3] = __builtin_nontemporal_load(wp_ + 3);                         \
    X2[0] = *(const bf16x8*)(xp_);                                       \
    X2[1] = *(const bf16x8*)(xp_ + 8);                                   \
  } while (0)

#define WRITE_LDS(W4, X2, h) do {                          \
    *(bf16x8*)&wbuf[h][soff]     = cvt8(W4[0], W4[1]);     \
    *(bf16x8*)&wbuf[h][soff + 8] = cvt8(W4[2], W4[3]);     \
    *(bf16x8*)&xbuf[h][soff]     = X2[0];                  \
    *(bf16x8*)&xbuf[h][soff + 8] = X2[1];                  \
  } while (0)

#define COMPUTE(h) do {                                    \
    _Pragma("unroll")                                      \
    for (int j_ = 0; j_ < 4; ++j_) {                       \
      bf16x8 bf_ = *(const bf16x8*)&wbuf[h][wfo + j_ * 32];\
      bf16x8 af_ = *(const bf16x8*)&xbuf[h][xfo + j_ * 32];\
      acc = __builtin_amdgcn_mfma_f32_16x16x32_bf16(af_, bf_, acc, 0, 0, 0); \
    }                                                      \
  } while (0)

  // lgkmcnt(0): our ds ops done; NO vmcnt drain -> prefetch survives barrier
#define BARRIER() do {                                     \
    asm volatile("s_waitcnt lgkmcnt(0)" ::: "memory");     \
    __builtin_amdgcn_s_barrier();                          \
  } while (0)

  f32x4 raw[4], rbw[4];
  bf16x8 rax[2], rbx[2];

  // prologue: chunk0 -> LDS[0]; chunk1 in flight
  ISSUE(raw, rax, 0);
  WRITE_LDS(raw, rax, 0);
  ISSUE(raw, rax, 1);
  BARRIER();

  for (int c = 0; c < NCHH; c += 2) {
    if (c + 2 < NCHH) ISSUE(rbw, rbx, c + 2);
    COMPUTE(0);
    WRITE_LDS(raw, rax, 1);                     // chunk c+1 (vmcnt counted)
    BARRIER();
    if (c + 3 < NCHH) ISSUE(raw, rax, c + 3);
    COMPUTE(1);
    if (c + 2 < NCHH) WRITE_LDS(rbw, rbx, 0);   // chunk c+2
    BARRIER();
  }

#undef ISSUE
#undef WRITE_LDS
#undef COMPUTE
#undef BARRIER

  // epilogue: reduce the 2 kq partials per (btile,potile) tile
  red[wv * 256 + lane * 4 + 0] = acc[0];
  red[wv * 256 + lane * 4 + 1] = acc[1];
  red[wv * 256 + lane * 4 + 2] = acc[2];
  red[wv * 256 + lane * 4 + 3] = acc[3];
  __syncthreads();

#pragma unroll
  for (int i0 = 0; i0 < 2; ++i0) {
    const int i    = i0 * 512 + t;     // 0..1023
    const int tile = i >> 8;           // potile*2 + btile
    const int slot = i & 255;
    const float v = red[tile * 256 + slot] + red[(tile + 4) * 256 + slot];
    const int ln = slot >> 2, rg = slot & 3;
    // D layout (m89/m91): col = lane&15 (po), row = (lane>>4)*4 + reg (b)
    const int b  = (tile & 1) * 16 + (ln >> 4) * 4 + rg;
    const int pl = (tile >> 1) * 16 + (ln & 15);
    part[((size_t)(kh * 128 + group) * 32 + b) * 32 + pl] = v;
  }
}

__global__ __launch_bounds__(256)
void combine(const float* __restrict__ part, const float* __restrict__ bias,
             float* __restrict__ out) {
  const int i = blockIdx.x * 256 + threadIdx.x;   // 0..131071 = (g*32+b)*32+pl
  const int pl = i & 31, b = (i >> 5) & 31, g = i >> 10;
  const float v = part[i] + part[131072 + i] + bias[g * 32 + pl];
  out[(size_t)b * NPO + g * 32 + pl] = v;
}

extern "C" void kernel_launch(void* const* d_in, const int* in_sizes, int n_in,
                              void* d_out, int out_size, void* d_ws, size_t ws_size,
                              hipStream_t stream) {
  const float* x    = (const float*)d_in[0];
  const float* wgt  = (const float*)d_in[1];
  const float* bias = (const float*)d_in[2];
  float* out = (float*)d_out;

  __bf16* xbf  = (__bf16*)d_ws;                        // 1 MB
  float*  part = (float*)((char*)d_ws + (1 << 20));    // 1 MB (2 k-halves)

  hipLaunchKernelGGL(precast_x, dim3(512), dim3(256), 0, stream, x, xbf);
  hipLaunchKernelGGL(trace_main, dim3(256), dim3(512), 0, stream, xbf, wgt, part);
  hipLaunchKernelGGL(combine, dim3(512), dim3(256), 0, stream, part, bias, out);
}

// Round 13
// 57.592 us; speedup vs baseline: 1.5184x; 1.5184x over previous
//
#include <hip/hip_runtime.h>

// out[b,po] = sum_k W[po,k]*x[b,k] + bias[po];  B=32, NPO=4096, K=16384.
// R13 = R9's 2-blocks/CU shape WITH precast (isolates R9's fp32-x confound).
// (1) precast x->bf16 (1 MB d_ws); (2) main: 512 blocks = 256 po-groups
// (POT=16) x 2 k-halves -> 2 independent blocks/CU (breaks one-block barrier
// lockstep; m114 co-scheduling). kh=blockIdx&1 constant per XCD -> shared
// 0.5 MB bf16 x half-slice (L2-resident). 32 chunks of 256 k; distance-2 reg
// prefetch -> bf16 LDS dbuf (WSTR 264); raw s_barrier + lgkmcnt(0) (no vmcnt
// drain). 8 waves = 2 btile x 4 kq, 2x mfma 16x16x32/chunk; LDS kq-reduce;
// fp32 partials. (3) combine: sum 2 halves + bias.

typedef __attribute__((ext_vector_type(8))) __bf16 bf16x8;
typedef __attribute__((ext_vector_type(4))) __bf16 bf16x4;
typedef __attribute__((ext_vector_type(4))) float f32x4;

#define KDIM 16384
#define NPO  4096
#define POT  16
#define CHK  256
#define KH   8192    // k per half
#define NCHH 32      // chunks per half
#define WSTR 264     // padded LDS k-stride (bf16): 528 B

__device__ inline bf16x8 cvt8(f32x4 a, f32x4 b) {
  bf16x8 r;
  r[0] = (__bf16)a.x; r[1] = (__bf16)a.y; r[2] = (__bf16)a.z; r[3] = (__bf16)a.w;
  r[4] = (__bf16)b.x; r[5] = (__bf16)b.y; r[6] = (__bf16)b.z; r[7] = (__bf16)b.w;
  return r;
}

__global__ __launch_bounds__(256)
void precast_x(const float* __restrict__ x, __bf16* __restrict__ xbf) {
  const int i = blockIdx.x * 256 + threadIdx.x;   // 131072 float4s
  f32x4 v = reinterpret_cast<const f32x4*>(x)[i];
  bf16x4 o;
  o[0] = (__bf16)v.x; o[1] = (__bf16)v.y; o[2] = (__bf16)v.z; o[3] = (__bf16)v.w;
  reinterpret_cast<bf16x4*>(xbf)[i] = o;
}

__global__ __launch_bounds__(512, 4)
void trace_main(const __bf16* __restrict__ xbf, const float* __restrict__ w,
                float* __restrict__ part) {
  __shared__ __bf16 wbuf[2][16 * WSTR];   // 16.9 KB
  __shared__ __bf16 xbuf[2][32 * WSTR];   // 33.8 KB
  __shared__ float  red[2048];            // 8 KB  -> 58.7 KB, 2 blocks/CU

  const int t    = threadIdx.x;
  const int lane = t & 63;
  const int wv   = t >> 6;       // 0..7
  const int btile = wv & 1;      // 16 batches each
  const int kq    = wv >> 1;     // 0..3: 64-k quarter of the 256-k chunk
  const int kh    = blockIdx.x & 1;    // constant per XCD
  const int group = blockIdx.x >> 1;   // po group (16 rows)
  const int po_base = group * POT;

  // staging coords: w 16r x 256c fp32 (8 f/thr), x 32r x 256c bf16 (16 e/thr)
  const int wrow_s = t >> 5, wcol_s = (t & 31) * 8;
  const int xrow_s = t >> 4, xcol_s = (t & 15) * 16;
  const float*  wg = w   + (size_t)(po_base + wrow_s) * KDIM + (size_t)kh * KH + wcol_s;
  const __bf16* xg = xbf + (size_t)xrow_s * KDIM + (size_t)kh * KH + xcol_s;
  const int woff = wrow_s * WSTR + wcol_s;
  const int xoff = xrow_s * WSTR + xcol_s;

  // fragment coords (A = x, B = w; same lane->k rule on both operands)
  const int lrow = lane & 15, lhi = lane >> 4;
  const int fk  = kq * 64 + lhi * 8;
  const int wfo = lrow * WSTR + fk;
  const int xfo = (btile * 16 + lrow) * WSTR + fk;

  f32x4 acc = {0.f, 0.f, 0.f, 0.f};

#define ISSUE(W2, X2, c) do {                              \
    const f32x4*  wp_ = (const f32x4*)(wg + (size_t)(c) * CHK); \
    const __bf16* xp_ = xg + (size_t)(c) * CHK;            \
    W2[0] = wp_[0];                                        \
    W2[1] = wp_[1];                                        \
    X2[0] = *(const bf16x8*)(xp_);                         \
    X2[1] = *(const bf16x8*)(xp_ + 8);                     \
  } while (0)

#define WRITE_LDS(W2, X2, h) do {                          \
    *(bf16x8*)&wbuf[h][woff]     = cvt8(W2[0], W2[1]);     \
    *(bf16x8*)&xbuf[h][xoff]     = X2[0];                  \
    *(bf16x8*)&xbuf[h][xoff + 8] = X2[1];                  \
  } while (0)

#define COMPUTE(h) do {                                    \
    _Pragma("unroll")                                      \
    for (int j_ = 0; j_ < 2; ++j_) {                       \
      bf16x8 bf_ = *(const bf16x8*)&wbuf[h][wfo + j_ * 32];\
      bf16x8 af_ = *(const bf16x8*)&xbuf[h][xfo + j_ * 32];\
      acc = __builtin_amdgcn_mfma_f32_16x16x32_bf16(af_, bf_, acc, 0, 0, 0); \
    }                                                      \
  } while (0)

  // lgkmcnt(0): our ds ops done; NO vmcnt drain -> prefetch survives barrier
#define BARRIER() do {                                     \
    asm volatile("s_waitcnt lgkmcnt(0)" ::: "memory");     \
    __builtin_amdgcn_s_barrier();                          \
  } while (0)

  f32x4 raw[2], rbw[2];
  bf16x8 rax[2], rbx[2];

  // prologue: chunk0 -> LDS[0]; chunk1 in flight
  ISSUE(raw, rax, 0);
  WRITE_LDS(raw, rax, 0);
  ISSUE(raw, rax, 1);
  BARRIER();

  for (int c = 0; c < NCHH; c += 2) {
    if (c + 2 < NCHH) ISSUE(rbw, rbx, c + 2);
    COMPUTE(0);
    WRITE_LDS(raw, rax, 1);                     // chunk c+1 (vmcnt counted)
    BARRIER();
    if (c + 3 < NCHH) ISSUE(raw, rax, c + 3);
    COMPUTE(1);
    if (c + 2 < NCHH) WRITE_LDS(rbw, rbx, 0);   // chunk c+2
    BARRIER();
  }

#undef ISSUE
#undef WRITE_LDS
#undef COMPUTE
#undef BARRIER

  // epilogue: reduce the 4 kq partials per btile
  red[wv * 256 + lane * 4 + 0] = acc[0];
  red[wv * 256 + lane * 4 + 1] = acc[1];
  red[wv * 256 + lane * 4 + 2] = acc[2];
  red[wv * 256 + lane * 4 + 3] = acc[3];
  __syncthreads();

  // 512 outputs: waves with btile bt2 are wv = bt2, bt2+2, bt2+4, bt2+6
  const int bt2  = t >> 8;          // btile
  const int slot = t & 255;
  const float v = red[bt2 * 256 + slot]        + red[bt2 * 256 + slot + 512]
                + red[bt2 * 256 + slot + 1024] + red[bt2 * 256 + slot + 1536];
  const int ln = slot >> 2, rg = slot & 3;
  // D layout (m89/m91): col = lane&15 (po), row = (lane>>4)*4 + reg (b)
  const int b  = bt2 * 16 + (ln >> 4) * 4 + rg;
  const int pl = ln & 15;
  part[((size_t)(kh * 256 + group) * 32 + b) * 16 + pl] = v;
}

__global__ __launch_bounds__(256)
void combine(const float* __restrict__ part, const float* __restrict__ bias,
             float* __restrict__ out) {
  const int i = blockIdx.x * 256 + threadIdx.x;   // 0..131071 = (g*32+b)*16+pl
  const int pl = i & 15, b = (i >> 4) & 31, g = i >> 9;
  const float v = part[i] + part[131072 + i] + bias[g * 16 + pl];
  out[(size_t)b * NPO + g * 16 + pl] = v;
}

extern "C" void kernel_launch(void* const* d_in, const int* in_sizes, int n_in,
                              void* d_out, int out_size, void* d_ws, size_t ws_size,
                              hipStream_t stream) {
  const float* x    = (const float*)d_in[0];
  const float* wgt  = (const float*)d_in[1];
  const float* bias = (const float*)d_in[2];
  float* out = (float*)d_out;

  __bf16* xbf  = (__bf16*)d_ws;                        // 1 MB
  float*  part = (float*)((char*)d_ws + (1 << 20));    // 1 MB (2 k-halves)

  hipLaunchKernelGGL(precast_x, dim3(512), dim3(256), 0, stream, x, xbf);
  hipLaunchKernelGGL(trace_main, dim3(512), dim3(512), 0, stream, xbf, wgt, part);
  hipLaunchKernelGGL(combine, dim3(512), dim3(256), 0, stream, part, bias, out);
}